// Round 11
// baseline (1118.032 us; speedup 1.0000x reference)
//
#include <hip/hip_runtime.h>
#include <hip/hip_bf16.h>

#define NNODES 12000
#define NEDGES 384000
#define NETOT  (NEDGES + NNODES)   /* 396000 incl self-loops */
#define FIN    4
#define FHID   50
#define FOUT   1433
#define KP     1440                /* FOUT padded to multiple of 32 */
#define MP     12032               /* NNODES padded: 94*128 = 47*256 */
#define GRID_G 2256                /* rect-tri tiles 128x256: sum(47 - (by>>1)) = 8*282 */
#define NEG_SLOPE 0.2f

typedef __hip_bfloat16 bf16_t;
typedef __bf16 bf16x8 __attribute__((ext_vector_type(8)));
typedef float f32x4 __attribute__((ext_vector_type(4)));
typedef float f32x2 __attribute__((ext_vector_type(2)));

__device__ __forceinline__ float  b2f(bf16_t h) { return __bfloat162float(h); }
__device__ __forceinline__ bf16_t f2b(float f)  { return __float2bfloat16(f); }
__device__ __forceinline__ unsigned short f2bu(float f) { bf16_t h = f2b(f); return *(unsigned short*)&h; }

// ---------------- init: deg=1 (self loop), zero pad rows of h2 (bf16) ----------------
__global__ void k_init(int* __restrict__ deg, bf16_t* __restrict__ h2) {
    int i = blockIdx.x * blockDim.x + threadIdx.x;
    int stride = gridDim.x * blockDim.x;
    for (int v = i; v < NNODES; v += stride) deg[v] = 1;
    const size_t padN = (size_t)(MP - NNODES) * KP;
    for (size_t t = i; t < padN; t += stride) h2[(size_t)NNODES * KP + t] = f2b(0.f);
}

// ---------------- count real edges by dst ----------------
__global__ void k_count(const int* __restrict__ ei, int* __restrict__ deg) {
    int i = blockIdx.x * blockDim.x + threadIdx.x;
    if (i < NEDGES) atomicAdd(&deg[ei[NEDGES + i]], 1);
}

// ---------------- single-block shfl exclusive scan -> rowptr[N+1] + cursor[N] ----------------
__global__ __launch_bounds__(1024) void k_scan(const int* __restrict__ deg,
                                               int* __restrict__ rowptr,
                                               int* __restrict__ cursor) {
    __shared__ int wsum[16];
    const int tid = threadIdx.x, lane = tid & 63, wv = tid >> 6;
    const int base = tid * 12;
    int pref[12];
    int s = 0;
#pragma unroll
    for (int u = 0; u < 12; ++u) {
        int idx = base + u;
        int d = (idx < NNODES) ? deg[idx] : 0;
        pref[u] = s;
        s += d;
    }
    int sc = s;   // inclusive wave scan of per-thread sums
#pragma unroll
    for (int o = 1; o < 64; o <<= 1) {
        int t2 = __shfl_up(sc, o, 64);
        if (lane >= o) sc += t2;
    }
    if (lane == 63) wsum[wv] = sc;
    __syncthreads();
    if (wv == 0 && lane < 16) {
        int mine = wsum[lane];
        int scw = mine;
#pragma unroll
        for (int o = 1; o < 16; o <<= 1) {
            int t3 = __shfl_up(scw, o, 64);
            if (lane >= o) scw += t3;
        }
        wsum[lane] = scw - mine;   // exclusive wave prefix
    }
    __syncthreads();
    const int pre = wsum[wv] + (sc - s);   // exclusive prefix of this thread
#pragma unroll
    for (int u = 0; u < 12; ++u) {
        int idx = base + u;
        if (idx < NNODES) {
            int p = pre + pref[u];
            rowptr[idx] = p;
            cursor[idx] = p;
        }
    }
    if (tid == 1023) rowptr[NNODES] = pre + s;   // == NETOT
}

// ---------------- fill CSR src lists (incl self loops) + edge passthrough ----------------
__global__ void k_fill(const int* __restrict__ ei, int* __restrict__ cursor,
                       int* __restrict__ csrc, float* __restrict__ outbase) {
    int i = blockIdx.x * blockDim.x + threadIdx.x;
    if (i < NETOT) {
        int s, d;
        if (i < NEDGES) { s = ei[i]; d = ei[NEDGES + i]; }
        else            { s = d = i - NEDGES; }
        int pos = atomicAdd(&cursor[d], 1);
        csrc[pos] = s;
    }
    if (i < 2 * NEDGES)
        outbase[(size_t)NNODES * (size_t)NNODES + (size_t)i] = (float)ei[i];
}

// ---------------- layer1 linear: h1pre = x @ W1, al1/ar1 logit parts ----------------
__global__ __launch_bounds__(256) void k_linear1(
        const bf16_t* __restrict__ x, const bf16_t* __restrict__ W1,
        const bf16_t* __restrict__ as1, const bf16_t* __restrict__ ad1,
        float* __restrict__ h1pre, float* __restrict__ al, float* __restrict__ ar) {
    __shared__ float sW[FIN * FHID];
    __shared__ float sa[FHID], sdl[FHID];
    int tid = threadIdx.x;
    if (tid < FIN * FHID) sW[tid] = b2f(W1[tid]);
    if (tid < FHID) { sa[tid] = b2f(as1[tid]); sdl[tid] = b2f(ad1[tid]); }
    __syncthreads();
    int i = blockIdx.x * 256 + tid;
    if (i >= NNODES) return;
    float x0 = b2f(x[i * 4 + 0]), x1 = b2f(x[i * 4 + 1]);
    float x2 = b2f(x[i * 4 + 2]), x3 = b2f(x[i * 4 + 3]);
    float hal = 0.f, har = 0.f;
    for (int j = 0; j < FHID; ++j) {
        float h = x0 * sW[j] + x1 * sW[FHID + j] + x2 * sW[2 * FHID + j] + x3 * sW[3 * FHID + j];
        h1pre[(size_t)i * FHID + j] = h;
        hal += h * sa[j];
        har += h * sdl[j];
    }
    al[i] = hal; ar[i] = har;
}

// ---------------- layer1 softmax-aggregate ----------------
__global__ __launch_bounds__(256) void k_agg1(
        const float* __restrict__ h1pre, const float* __restrict__ al, const float* __restrict__ ar,
        const int* __restrict__ rowptr, const int* __restrict__ csrc,
        const bf16_t* __restrict__ b1, float* __restrict__ h1) {
    const int wv = threadIdx.x >> 6, lane = threadIdx.x & 63;
    const int v = blockIdx.x * 4 + wv;        // NNODES % 4 == 0
    const int s0 = rowptr[v], s1 = rowptr[v + 1];
    const float arv = ar[v];
    float acc = 0.f, ssum = 0.f;
    for (int base = s0; base < s1; base += 64) {
        int e = base + lane;
        float w = 0.f; int si = 0;
        if (e < s1) {
            si = csrc[e];
            float l = al[si] + arv;
            l = l > 0.f ? l : NEG_SLOPE * l;
            w = __expf(l);                     // softmax is shift-invariant; |l| small
        }
        ssum += w;
        int cnt = min(64, s1 - base);
#pragma unroll 4
        for (int j = 0; j < cnt; ++j) {
            float wj = __shfl(w, j, 64);
            int   sj = __shfl(si, j, 64);
            if (lane < FHID) acc += wj * h1pre[(size_t)sj * FHID + lane];
        }
    }
#pragma unroll
    for (int o = 32; o; o >>= 1) ssum += __shfl_xor(ssum, o, 64);
    if (lane < FHID) {
        float o2 = acc / ssum + b2f(b1[lane]);
        h1[(size_t)v * FHID + lane] = fmaxf(o2, 0.f);
    }
}

// ---------------- layer2 linear: 4 nodes/block, h2pre (fp8 e4m3) = h1 @ W2, al2/ar2 ----------------
__global__ __launch_bounds__(256) void k_linear2(
        const float* __restrict__ h1, const bf16_t* __restrict__ W2,
        const bf16_t* __restrict__ as2, const bf16_t* __restrict__ ad2,
        unsigned char* __restrict__ h2pre, float* __restrict__ al2, float* __restrict__ ar2) {
    int v0 = blockIdx.x * 4, tid = threadIdx.x;
    __shared__ float sh[4][FHID];
    if (tid < 4 * FHID) sh[tid / FHID][tid % FHID] = h1[(size_t)v0 * FHID + tid];
    __syncthreads();
    float pal[4] = {0.f, 0.f, 0.f, 0.f}, par[4] = {0.f, 0.f, 0.f, 0.f};
#pragma unroll
    for (int i = 0; i < 3; ++i) {
        int f0 = i * 512 + 2 * tid;          // even feature index
        if (f0 < KP) {
            float d0[4] = {0.f, 0.f, 0.f, 0.f}, d1[4] = {0.f, 0.f, 0.f, 0.f};
            bool ok0 = f0 < FOUT, ok1 = f0 + 1 < FOUT;
            if (ok0) {
                int f1 = ok1 ? f0 + 1 : f0;  // safe aliased read when f0+1 OOB
#pragma unroll 10
                for (int k = 0; k < FHID; ++k) {
                    float w0 = b2f(W2[k * FOUT + f0]);
                    float w1 = b2f(W2[k * FOUT + f1]);
#pragma unroll
                    for (int c = 0; c < 4; ++c) {
                        d0[c] += sh[c][k] * w0;
                        d1[c] += sh[c][k] * w1;
                    }
                }
                if (!ok1) { d1[0] = d1[1] = d1[2] = d1[3] = 0.f; }
                float sa0 = b2f(as2[f0]), sd0 = b2f(ad2[f0]);
                float sa1 = ok1 ? b2f(as2[f0 + 1]) : 0.f;
                float sd1 = ok1 ? b2f(ad2[f0 + 1]) : 0.f;
#pragma unroll
                for (int c = 0; c < 4; ++c) {
                    pal[c] += d0[c] * sa0 + d1[c] * sa1;
                    par[c] += d0[c] * sd0 + d1[c] * sd1;
                }
            }
#pragma unroll
            for (int c = 0; c < 4; ++c) {
                int pk = __builtin_amdgcn_cvt_pk_fp8_f32(d0[c], d1[c], 0, false);
                *(unsigned short*)(h2pre + (size_t)(v0 + c) * KP + f0) = (unsigned short)pk;
            }
        }
    }
#pragma unroll
    for (int off = 32; off; off >>= 1)
#pragma unroll
        for (int c = 0; c < 4; ++c) {
            pal[c] += __shfl_xor(pal[c], off, 64);
            par[c] += __shfl_xor(par[c], off, 64);
        }
    __shared__ float rA[4][4], rB[4][4];
    int wave = tid >> 6, lane = tid & 63;
    if (lane == 0)
#pragma unroll
        for (int c = 0; c < 4; ++c) { rA[wave][c] = pal[c]; rB[wave][c] = par[c]; }
    __syncthreads();
    if (tid < 4) {
        al2[v0 + tid] = rA[0][tid] + rA[1][tid] + rA[2][tid] + rA[3][tid];
        ar2[v0 + tid] = rB[0][tid] + rB[1][tid] + rB[2][tid] + rB[3][tid];
    }
}

// ---------------- layer2 softmax-aggregate: fp8 gather, no max pass, bf16 h2 out ----------------
__global__ __launch_bounds__(256) void k_agg2(
        const unsigned char* __restrict__ h2pre, const float* __restrict__ al, const float* __restrict__ ar,
        const int* __restrict__ rowptr, const int* __restrict__ csrc,
        const bf16_t* __restrict__ bias2, bf16_t* __restrict__ h2) {
    int v = blockIdx.x, tid = threadIdx.x;
    int s0 = rowptr[v], s1 = rowptr[v + 1];
    float arv = ar[v];
    int wave = tid >> 6, lane = tid & 63;

    float acc[8] = {0.f, 0.f, 0.f, 0.f, 0.f, 0.f, 0.f, 0.f};
    float ssum = 0.f;
    __shared__ float sw[256];
    __shared__ int ssrc[256];
    __shared__ float red[4];
    const bool act = tid < (KP / 8);          // 180 lanes cover the 1440-B row
    for (int base = s0; base < s1; base += 256) {
        int e = base + tid;
        float w = 0.f; int si = 0;
        if (e < s1) {
            si = csrc[e];
            float l = al[si] + arv;
            l = l > 0.f ? l : NEG_SLOPE * l;
            w = __expf(l);                    // shift-invariant; |l| small
        }
        ssum += w;
        sw[tid] = w; ssrc[tid] = si;
        __syncthreads();
        int cnt = min(256, s1 - base);
        if (act) {
#pragma unroll 8
            for (int j = 0; j < cnt; ++j) {
                float wj = sw[j];
                const uint2* hp = (const uint2*)(h2pre + (size_t)ssrc[j] * KP);
                uint2 p = hp[tid];
                f32x2 e0 = __builtin_amdgcn_cvt_pk_f32_fp8(p.x, false);
                f32x2 e1 = __builtin_amdgcn_cvt_pk_f32_fp8(p.x, true);
                f32x2 e2 = __builtin_amdgcn_cvt_pk_f32_fp8(p.y, false);
                f32x2 e3 = __builtin_amdgcn_cvt_pk_f32_fp8(p.y, true);
                acc[0] += wj * e0.x; acc[1] += wj * e0.y;
                acc[2] += wj * e1.x; acc[3] += wj * e1.y;
                acc[4] += wj * e2.x; acc[5] += wj * e2.y;
                acc[6] += wj * e3.x; acc[7] += wj * e3.y;
            }
        }
        __syncthreads();
    }
#pragma unroll
    for (int off = 32; off; off >>= 1) ssum += __shfl_xor(ssum, off, 64);
    if (lane == 0) red[wave] = ssum;
    __syncthreads();
    float inv = 1.f / (red[0] + red[1] + red[2] + red[3]);

    if (act) {
        int fb = 8 * tid;
        unsigned short o[8];
#pragma unroll
        for (int t = 0; t < 8; ++t) {
            int f = fb + t;
            o[t] = f2bu((f < FOUT) ? fmaxf(acc[t] * inv + b2f(bias2[f]), 0.f) : 0.f);
        }
        uint4 pk;
        pk.x = (unsigned)o[0] | ((unsigned)o[1] << 16);
        pk.y = (unsigned)o[2] | ((unsigned)o[3] << 16);
        pk.z = (unsigned)o[4] | ((unsigned)o[5] << 16);
        pk.w = (unsigned)o[6] | ((unsigned)o[7] << 16);
        *(uint4*)(h2 + (size_t)v * KP + fb) = pk;
    }
}

// ---------------- final: out = sigmoid(H @ H^T), 128x256 MFMA GEMM ----------------
// Round-11: B-IN-REGISTERS.  R10's barrier/stage-timing change was exactly
// null -> the step time sits in the barrier-coupled DMA path (12 gload_lds
// per CU per step through one vmcnt gate).  Key fact of the 128x256 geometry:
// each wave reads a DISJOINT 64-row stripe of B, so LDS staging of B shares
// nothing across waves.  This round B is loaded global->VGPR per wave,
// double-buffered one K-step ahead (b0/b1 ping-pong, 2x-unrolled loop so all
// register indices are static).  Removes 4 of 6 barrier-guarded DMAs and 4 of
// 12 per-wave ds_reads; frees 48 KB LDS (A-only ring: 3 x 8 KB).  A keeps the
// LDS ring (shared by all 4 waves, 2-step prefetch).  FIFO per step kt:
// outstanding = [A(kt)x2, B(kt)x4, A(kt+1)x2]; vmcnt(2) drains exactly
// A(kt)+B(kt).  Tail: step 44 waits vmcnt(0).  Same grouped-triangular decode,
// XCD chunking, rect-tri coverage + mirror writes as R9/R10.
__global__ __launch_bounds__(256, 2) void k_gemm_sig(const bf16_t* __restrict__ Hm,
                                                     float* __restrict__ out) {
    // XCD-bijective chunk swizzle (2256 = 8*282)
    int orig = blockIdx.x;
    int tt = (orig & 7) * (GRID_G / 8) + (orig >> 3);

    // grouped decode: groups of 8 by-rows (last 6), bx-major inside a group
    int u = tt, by0 = 88, R = 6;
#pragma unroll 1
    for (int g = 0; g < 12; ++g) {
        int Rg = (g == 11) ? 6 : 8;
        int sz = (g == 11) ? 12 : (364 - 32 * g);
        if (u < sz) { by0 = 8 * g; R = Rg; break; }
        u -= sz;
    }
    int d = 0;
#pragma unroll 1
    for (;;) {
        int s = 2 * d + 2; if (s > R) s = R;
        if (u < s) break;
        u -= s; ++d;
    }
    const int by = by0 + u;
    const int bx = (by0 >> 1) + d;

    __shared__ __align__(16) char As[3 * 8192];   // A-only ring: 3 slots x 128x32 bf16

    const int tid  = threadIdx.x;
    const int wave = tid >> 6, lane = tid & 63;
    const int rowA0 = by * 128;          // C rows
    const int colC0 = bx * 256;          // C cols = B rows
    const int r = lane & 15, q4 = lane >> 4;

    // A staging: thread covers 16 B at (row = c*64 + tid>>2, elem col = (tid&3)*8)
    const bf16_t* gA = Hm + (size_t)(rowA0 + (tid >> 2)) * KP + (tid & 3) * 8;
    // B fragment global base: row = colC0 + wave*64 + ni*16 + r, col = kt*32 + q4*8
    const bf16_t* gB0 = Hm + (size_t)(colC0 + wave * 64 + r) * KP + q4 * 8;

    // A fragment read offset (row stride 64 B within a slot)
    const int aOff = r * 64 + q4 * 16;   // + mi*1024

    f32x4 acc[8][4] = {};
    bf16x8 b0[4], b1[4];

// stage A K-step kt_ into ring slot sl_: 2 gload_lds per thread
#define STAGE_A(sl_, kt_) do {                                                    \
        const int k0_ = (kt_) * 32;                                               \
        _Pragma("unroll")                                                         \
        for (int c_ = 0; c_ < 2; ++c_)                                            \
            __builtin_amdgcn_global_load_lds(                                     \
                (const __attribute__((address_space(1))) void*)(gA + (size_t)(c_ * 64) * KP + k0_), \
                (__attribute__((address_space(3))) void*)(As + (sl_) * 8192 + c_ * 4096 + tid * 16), \
                16, 0, 0);                                                        \
    } while (0)

// load B fragments for K-step kt_ into register array dst_ (4 global_load_dwordx4)
#define LOADB(dst_, kt_) { _Pragma("unroll") for (int n_ = 0; n_ < 4; ++n_)       \
        dst_[n_] = *(const bf16x8*)(gB0 + (size_t)(n_ * 16) * KP + (kt_) * 32); }

// one K-step's compute: A from LDS slot sl_, B from register array bb_
#define COMPUTE(sl_, bb_) {                                                       \
        const char* S_ = As + (sl_) * 8192;                                       \
        bf16x8 af_[4];                                                            \
        _Pragma("unroll") for (int mi = 0; mi < 4; ++mi)                          \
            af_[mi] = *(const bf16x8*)(S_ + aOff + mi * 1024);                    \
        __builtin_amdgcn_s_setprio(1);                                            \
        _Pragma("unroll") for (int mi = 0; mi < 4; ++mi)                          \
        _Pragma("unroll") for (int ni = 0; ni < 4; ++ni)                          \
            acc[mi][ni] = __builtin_amdgcn_mfma_f32_16x16x32_bf16(af_[mi], bb_[ni], acc[mi][ni], 0, 0, 0); \
        _Pragma("unroll") for (int mi = 0; mi < 4; ++mi)                          \
            af_[mi] = *(const bf16x8*)(S_ + aOff + (mi + 4) * 1024);              \
        _Pragma("unroll") for (int mi = 0; mi < 4; ++mi)                          \
        _Pragma("unroll") for (int ni = 0; ni < 4; ++ni)                          \
            acc[mi + 4][ni] = __builtin_amdgcn_mfma_f32_16x16x32_bf16(af_[mi], bb_[ni], acc[mi + 4][ni], 0, 0, 0); \
        __builtin_amdgcn_s_setprio(0); }

    // prologue: A(0)->slot0, B(0)->b0, A(1)->slot1  (FIFO: A0x2, B0x4, A1x2)
    STAGE_A(0, 0);
    LOADB(b0, 0);
    STAGE_A(1, 1);

    int sl = 0;   // slot of the even step
#pragma unroll 1
    for (int kt = 0; kt < 44; kt += 2) {
        // even step kt: slot sl, b0
        asm volatile("s_waitcnt vmcnt(2)" ::: "memory");   // A(kt)+B(kt) landed
        __builtin_amdgcn_s_barrier();
        __builtin_amdgcn_sched_barrier(0);
        LOADB(b1, kt + 1);
        STAGE_A((sl + 2) % 3, kt + 2);                     // kt+2 <= 44 always
        COMPUTE(sl, b0);
        __builtin_amdgcn_sched_barrier(0);
        // odd step kt+1: slot (sl+1)%3, b1
        asm volatile("s_waitcnt vmcnt(2)" ::: "memory");   // A(kt+1)+B(kt+1) landed
        __builtin_amdgcn_s_barrier();
        __builtin_amdgcn_sched_barrier(0);
        LOADB(b0, kt + 2);                                 // kt+2 <= 44 always
        if (kt + 3 < 45) STAGE_A((sl + 3) % 3, kt + 3);
        COMPUTE((sl + 1) % 3, b1);
        __builtin_amdgcn_sched_barrier(0);
        sl = (sl + 2) % 3;
    }
    // final step kt=44: slot sl, b0
    asm volatile("s_waitcnt vmcnt(0)" ::: "memory");
    __builtin_amdgcn_s_barrier();
    __builtin_amdgcn_sched_barrier(0);
    COMPUTE(sl, b0);
#undef STAGE_A
#undef LOADB
#undef COMPUTE

    // epilogue. C/D layout: col=lane&15, row=(lane>>4)*4+reg. NNODES%4==0.
    // Direct store + unconditional mirror store (overlaps write equal values).
#pragma unroll
    for (int mi = 0; mi < 8; ++mi) {
        const int row0 = rowA0 + mi * 16 + q4 * 4;
#pragma unroll
        for (int ni = 0; ni < 4; ++ni) {
            const int col = colC0 + wave * 64 + ni * 16 + r;
            if (col < NNODES && row0 < NNODES) {
                f32x4 s;
#pragma unroll
                for (int r2 = 0; r2 < 4; ++r2)
                    s[r2] = 1.f / (1.f + __expf(-acc[mi][ni][r2]));
#pragma unroll
                for (int r2 = 0; r2 < 4; ++r2)
                    out[(size_t)(row0 + r2) * NNODES + col] = s[r2];
                *(f32x4*)(out + (size_t)col * NNODES + row0) = s;   // mirror
            }
        }
    }
}

extern "C" void kernel_launch(void* const* d_in, const int* in_sizes, int n_in,
                              void* d_out, int out_size, void* d_ws, size_t ws_size,
                              hipStream_t stream) {
    const bf16_t* x   = (const bf16_t*)d_in[0];
    const int*    ei  = (const int*)d_in[1];
    const bf16_t* W1  = (const bf16_t*)d_in[2];
    const bf16_t* as1 = (const bf16_t*)d_in[3];
    const bf16_t* ad1 = (const bf16_t*)d_in[4];
    const bf16_t* b1  = (const bf16_t*)d_in[5];
    const bf16_t* W2  = (const bf16_t*)d_in[6];
    const bf16_t* as2 = (const bf16_t*)d_in[7];
    const bf16_t* ad2 = (const bf16_t*)d_in[8];
    const bf16_t* b2  = (const bf16_t*)d_in[9];
    float* out = (float*)d_out;   // output 0 f32 [N][N], output 1 f32 [2][E]

    // Scratch lives inside d_out's adjacency region (576 MB f32), dead until
    // k_gemm_sig overwrites it. Only h2 (read during final GEMM) is in d_ws.
    char* obuf = (char*)d_out;
    size_t off = 0;
    auto carve = [&](size_t bytes) {
        char* p = obuf + off;
        off += (bytes + 255) & ~(size_t)255;
        return p;
    };
    float* h1pre  = (float*)carve((size_t)NNODES * FHID * 4);
    float* al1    = (float*)carve((size_t)NNODES * 4);
    float* ar1    = (float*)carve((size_t)NNODES * 4);
    float* h1     = (float*)carve((size_t)NNODES * FHID * 4);
    float* al2    = (float*)carve((size_t)NNODES * 4);
    float* ar2    = (float*)carve((size_t)NNODES * 4);
    int*   deg    = (int*)carve((size_t)NNODES * 4);
    int*   rowptr = (int*)carve((size_t)(NNODES + 1) * 4);
    int*   cursor = (int*)carve((size_t)NNODES * 4);
    int*   csrc   = (int*)carve((size_t)NETOT * 4);
    unsigned char* h2pre = (unsigned char*)carve((size_t)NNODES * KP);  // fp8
    bf16_t* h2 = (bf16_t*)d_ws;   // [MP][KP] bf16 = 34.65 MB
    (void)ws_size; (void)in_sizes; (void)n_in; (void)out_size;

    hipLaunchKernelGGL(k_init,    dim3(256), dim3(256), 0, stream, deg, h2);
    hipLaunchKernelGGL(k_count,   dim3((NEDGES + 255) / 256), dim3(256), 0, stream, ei, deg);
    hipLaunchKernelGGL(k_scan,    dim3(1), dim3(1024), 0, stream, deg, rowptr, cursor);
    hipLaunchKernelGGL(k_fill,    dim3((2 * NEDGES + 255) / 256), dim3(256), 0, stream,
                       ei, cursor, csrc, out);
    hipLaunchKernelGGL(k_linear1, dim3((NNODES + 255) / 256), dim3(256), 0, stream,
                       x, W1, as1, ad1, h1pre, al1, ar1);
    hipLaunchKernelGGL(k_agg1,    dim3(NNODES / 4), dim3(256), 0, stream,
                       h1pre, al1, ar1, rowptr, csrc, b1, h1);
    hipLaunchKernelGGL(k_linear2, dim3(NNODES / 4), dim3(256), 0, stream,
                       h1, W2, as2, ad2, h2pre, al2, ar2);
    hipLaunchKernelGGL(k_agg2,    dim3(NNODES), dim3(256), 0, stream,
                       h2pre, al2, ar2, rowptr, csrc, b2, h2);
    hipLaunchKernelGGL(k_gemm_sig, dim3(GRID_G), dim3(256), 0, stream, h2, out);
}

// Round 12
// 1091.392 us; speedup vs baseline: 1.0244x; 1.0244x over previous
//
#include <hip/hip_runtime.h>
#include <hip/hip_bf16.h>

#define NNODES 12000
#define NEDGES 384000
#define NETOT  (NEDGES + NNODES)   /* 396000 incl self-loops */
#define FIN    4
#define FHID   50
#define FOUT   1433
#define KP     1440                /* FOUT padded to multiple of 32 */
#define MP     12032               /* NNODES padded: 94*128 = 47*256 */
#define GRID_G 2256                /* rect-tri tiles 128x256: sum(47 - (by>>1)) = 8*282 */
#define NEG_SLOPE 0.2f

typedef __hip_bfloat16 bf16_t;
typedef __bf16 bf16x8 __attribute__((ext_vector_type(8)));
typedef float f32x4 __attribute__((ext_vector_type(4)));
typedef float f32x2 __attribute__((ext_vector_type(2)));

__device__ __forceinline__ float  b2f(bf16_t h) { return __bfloat162float(h); }
__device__ __forceinline__ bf16_t f2b(float f)  { return __float2bfloat16(f); }
__device__ __forceinline__ unsigned short f2bu(float f) { bf16_t h = f2b(f); return *(unsigned short*)&h; }

// ---------------- init: deg=1 (self loop), zero pad rows of h2 (bf16) ----------------
__global__ void k_init(int* __restrict__ deg, bf16_t* __restrict__ h2) {
    int i = blockIdx.x * blockDim.x + threadIdx.x;
    int stride = gridDim.x * blockDim.x;
    for (int v = i; v < NNODES; v += stride) deg[v] = 1;
    const size_t padN = (size_t)(MP - NNODES) * KP;
    for (size_t t = i; t < padN; t += stride) h2[(size_t)NNODES * KP + t] = f2b(0.f);
}

// ---------------- count real edges by dst ----------------
__global__ void k_count(const int* __restrict__ ei, int* __restrict__ deg) {
    int i = blockIdx.x * blockDim.x + threadIdx.x;
    if (i < NEDGES) atomicAdd(&deg[ei[NEDGES + i]], 1);
}

// ---------------- single-block shfl exclusive scan -> rowptr[N+1] + cursor[N] ----------------
__global__ __launch_bounds__(1024) void k_scan(const int* __restrict__ deg,
                                               int* __restrict__ rowptr,
                                               int* __restrict__ cursor) {
    __shared__ int wsum[16];
    const int tid = threadIdx.x, lane = tid & 63, wv = tid >> 6;
    const int base = tid * 12;
    int pref[12];
    int s = 0;
#pragma unroll
    for (int u = 0; u < 12; ++u) {
        int idx = base + u;
        int d = (idx < NNODES) ? deg[idx] : 0;
        pref[u] = s;
        s += d;
    }
    int sc = s;   // inclusive wave scan of per-thread sums
#pragma unroll
    for (int o = 1; o < 64; o <<= 1) {
        int t2 = __shfl_up(sc, o, 64);
        if (lane >= o) sc += t2;
    }
    if (lane == 63) wsum[wv] = sc;
    __syncthreads();
    if (wv == 0 && lane < 16) {
        int mine = wsum[lane];
        int scw = mine;
#pragma unroll
        for (int o = 1; o < 16; o <<= 1) {
            int t3 = __shfl_up(scw, o, 64);
            if (lane >= o) scw += t3;
        }
        wsum[lane] = scw - mine;   // exclusive wave prefix
    }
    __syncthreads();
    const int pre = wsum[wv] + (sc - s);   // exclusive prefix of this thread
#pragma unroll
    for (int u = 0; u < 12; ++u) {
        int idx = base + u;
        if (idx < NNODES) {
            int p = pre + pref[u];
            rowptr[idx] = p;
            cursor[idx] = p;
        }
    }
    if (tid == 1023) rowptr[NNODES] = pre + s;   // == NETOT
}

// ---------------- fill CSR src lists (incl self loops) + edge passthrough ----------------
__global__ void k_fill(const int* __restrict__ ei, int* __restrict__ cursor,
                       int* __restrict__ csrc, float* __restrict__ outbase) {
    int i = blockIdx.x * blockDim.x + threadIdx.x;
    if (i < NETOT) {
        int s, d;
        if (i < NEDGES) { s = ei[i]; d = ei[NEDGES + i]; }
        else            { s = d = i - NEDGES; }
        int pos = atomicAdd(&cursor[d], 1);
        csrc[pos] = s;
    }
    if (i < 2 * NEDGES)
        outbase[(size_t)NNODES * (size_t)NNODES + (size_t)i] = (float)ei[i];
}

// ---------------- layer1 linear: h1pre = x @ W1, al1/ar1 logit parts ----------------
__global__ __launch_bounds__(256) void k_linear1(
        const bf16_t* __restrict__ x, const bf16_t* __restrict__ W1,
        const bf16_t* __restrict__ as1, const bf16_t* __restrict__ ad1,
        float* __restrict__ h1pre, float* __restrict__ al, float* __restrict__ ar) {
    __shared__ float sW[FIN * FHID];
    __shared__ float sa[FHID], sdl[FHID];
    int tid = threadIdx.x;
    if (tid < FIN * FHID) sW[tid] = b2f(W1[tid]);
    if (tid < FHID) { sa[tid] = b2f(as1[tid]); sdl[tid] = b2f(ad1[tid]); }
    __syncthreads();
    int i = blockIdx.x * 256 + tid;
    if (i >= NNODES) return;
    float x0 = b2f(x[i * 4 + 0]), x1 = b2f(x[i * 4 + 1]);
    float x2 = b2f(x[i * 4 + 2]), x3 = b2f(x[i * 4 + 3]);
    float hal = 0.f, har = 0.f;
    for (int j = 0; j < FHID; ++j) {
        float h = x0 * sW[j] + x1 * sW[FHID + j] + x2 * sW[2 * FHID + j] + x3 * sW[3 * FHID + j];
        h1pre[(size_t)i * FHID + j] = h;
        hal += h * sa[j];
        har += h * sdl[j];
    }
    al[i] = hal; ar[i] = har;
}

// ---------------- layer1 softmax-aggregate ----------------
__global__ __launch_bounds__(256) void k_agg1(
        const float* __restrict__ h1pre, const float* __restrict__ al, const float* __restrict__ ar,
        const int* __restrict__ rowptr, const int* __restrict__ csrc,
        const bf16_t* __restrict__ b1, float* __restrict__ h1) {
    const int wv = threadIdx.x >> 6, lane = threadIdx.x & 63;
    const int v = blockIdx.x * 4 + wv;        // NNODES % 4 == 0
    const int s0 = rowptr[v], s1 = rowptr[v + 1];
    const float arv = ar[v];
    float acc = 0.f, ssum = 0.f;
    for (int base = s0; base < s1; base += 64) {
        int e = base + lane;
        float w = 0.f; int si = 0;
        if (e < s1) {
            si = csrc[e];
            float l = al[si] + arv;
            l = l > 0.f ? l : NEG_SLOPE * l;
            w = __expf(l);                     // softmax is shift-invariant; |l| small
        }
        ssum += w;
        int cnt = min(64, s1 - base);
#pragma unroll 4
        for (int j = 0; j < cnt; ++j) {
            float wj = __shfl(w, j, 64);
            int   sj = __shfl(si, j, 64);
            if (lane < FHID) acc += wj * h1pre[(size_t)sj * FHID + lane];
        }
    }
#pragma unroll
    for (int o = 32; o; o >>= 1) ssum += __shfl_xor(ssum, o, 64);
    if (lane < FHID) {
        float o2 = acc / ssum + b2f(b1[lane]);
        h1[(size_t)v * FHID + lane] = fmaxf(o2, 0.f);
    }
}

// ---------------- layer2 linear: 4 nodes/block, h2pre (fp8 e4m3) = h1 @ W2, al2/ar2 ----------------
__global__ __launch_bounds__(256) void k_linear2(
        const float* __restrict__ h1, const bf16_t* __restrict__ W2,
        const bf16_t* __restrict__ as2, const bf16_t* __restrict__ ad2,
        unsigned char* __restrict__ h2pre, float* __restrict__ al2, float* __restrict__ ar2) {
    int v0 = blockIdx.x * 4, tid = threadIdx.x;
    __shared__ float sh[4][FHID];
    if (tid < 4 * FHID) sh[tid / FHID][tid % FHID] = h1[(size_t)v0 * FHID + tid];
    __syncthreads();
    float pal[4] = {0.f, 0.f, 0.f, 0.f}, par[4] = {0.f, 0.f, 0.f, 0.f};
#pragma unroll
    for (int i = 0; i < 3; ++i) {
        int f0 = i * 512 + 2 * tid;          // even feature index
        if (f0 < KP) {
            float d0[4] = {0.f, 0.f, 0.f, 0.f}, d1[4] = {0.f, 0.f, 0.f, 0.f};
            bool ok0 = f0 < FOUT, ok1 = f0 + 1 < FOUT;
            if (ok0) {
                int f1 = ok1 ? f0 + 1 : f0;  // safe aliased read when f0+1 OOB
#pragma unroll 10
                for (int k = 0; k < FHID; ++k) {
                    float w0 = b2f(W2[k * FOUT + f0]);
                    float w1 = b2f(W2[k * FOUT + f1]);
#pragma unroll
                    for (int c = 0; c < 4; ++c) {
                        d0[c] += sh[c][k] * w0;
                        d1[c] += sh[c][k] * w1;
                    }
                }
                if (!ok1) { d1[0] = d1[1] = d1[2] = d1[3] = 0.f; }
                float sa0 = b2f(as2[f0]), sd0 = b2f(ad2[f0]);
                float sa1 = ok1 ? b2f(as2[f0 + 1]) : 0.f;
                float sd1 = ok1 ? b2f(ad2[f0 + 1]) : 0.f;
#pragma unroll
                for (int c = 0; c < 4; ++c) {
                    pal[c] += d0[c] * sa0 + d1[c] * sa1;
                    par[c] += d0[c] * sd0 + d1[c] * sd1;
                }
            }
#pragma unroll
            for (int c = 0; c < 4; ++c) {
                int pk = __builtin_amdgcn_cvt_pk_fp8_f32(d0[c], d1[c], 0, false);
                *(unsigned short*)(h2pre + (size_t)(v0 + c) * KP + f0) = (unsigned short)pk;
            }
        }
    }
#pragma unroll
    for (int off = 32; off; off >>= 1)
#pragma unroll
        for (int c = 0; c < 4; ++c) {
            pal[c] += __shfl_xor(pal[c], off, 64);
            par[c] += __shfl_xor(par[c], off, 64);
        }
    __shared__ float rA[4][4], rB[4][4];
    int wave = tid >> 6, lane = tid & 63;
    if (lane == 0)
#pragma unroll
        for (int c = 0; c < 4; ++c) { rA[wave][c] = pal[c]; rB[wave][c] = par[c]; }
    __syncthreads();
    if (tid < 4) {
        al2[v0 + tid] = rA[0][tid] + rA[1][tid] + rA[2][tid] + rA[3][tid];
        ar2[v0 + tid] = rB[0][tid] + rB[1][tid] + rB[2][tid] + rB[3][tid];
    }
}

// ---------------- layer2 softmax-aggregate: fp8 gather, no max pass, bf16 h2 out ----------------
__global__ __launch_bounds__(256) void k_agg2(
        const unsigned char* __restrict__ h2pre, const float* __restrict__ al, const float* __restrict__ ar,
        const int* __restrict__ rowptr, const int* __restrict__ csrc,
        const bf16_t* __restrict__ bias2, bf16_t* __restrict__ h2) {
    int v = blockIdx.x, tid = threadIdx.x;
    int s0 = rowptr[v], s1 = rowptr[v + 1];
    float arv = ar[v];
    int wave = tid >> 6, lane = tid & 63;

    float acc[8] = {0.f, 0.f, 0.f, 0.f, 0.f, 0.f, 0.f, 0.f};
    float ssum = 0.f;
    __shared__ float sw[256];
    __shared__ int ssrc[256];
    __shared__ float red[4];
    const bool act = tid < (KP / 8);          // 180 lanes cover the 1440-B row
    for (int base = s0; base < s1; base += 256) {
        int e = base + tid;
        float w = 0.f; int si = 0;
        if (e < s1) {
            si = csrc[e];
            float l = al[si] + arv;
            l = l > 0.f ? l : NEG_SLOPE * l;
            w = __expf(l);                    // shift-invariant; |l| small
        }
        ssum += w;
        sw[tid] = w; ssrc[tid] = si;
        __syncthreads();
        int cnt = min(256, s1 - base);
        if (act) {
#pragma unroll 8
            for (int j = 0; j < cnt; ++j) {
                float wj = sw[j];
                const uint2* hp = (const uint2*)(h2pre + (size_t)ssrc[j] * KP);
                uint2 p = hp[tid];
                f32x2 e0 = __builtin_amdgcn_cvt_pk_f32_fp8(p.x, false);
                f32x2 e1 = __builtin_amdgcn_cvt_pk_f32_fp8(p.x, true);
                f32x2 e2 = __builtin_amdgcn_cvt_pk_f32_fp8(p.y, false);
                f32x2 e3 = __builtin_amdgcn_cvt_pk_f32_fp8(p.y, true);
                acc[0] += wj * e0.x; acc[1] += wj * e0.y;
                acc[2] += wj * e1.x; acc[3] += wj * e1.y;
                acc[4] += wj * e2.x; acc[5] += wj * e2.y;
                acc[6] += wj * e3.x; acc[7] += wj * e3.y;
            }
        }
        __syncthreads();
    }
#pragma unroll
    for (int off = 32; off; off >>= 1) ssum += __shfl_xor(ssum, off, 64);
    if (lane == 0) red[wave] = ssum;
    __syncthreads();
    float inv = 1.f / (red[0] + red[1] + red[2] + red[3]);

    if (act) {
        int fb = 8 * tid;
        unsigned short o[8];
#pragma unroll
        for (int t = 0; t < 8; ++t) {
            int f = fb + t;
            o[t] = f2bu((f < FOUT) ? fmaxf(acc[t] * inv + b2f(bias2[f]), 0.f) : 0.f);
        }
        uint4 pk;
        pk.x = (unsigned)o[0] | ((unsigned)o[1] << 16);
        pk.y = (unsigned)o[2] | ((unsigned)o[3] << 16);
        pk.z = (unsigned)o[4] | ((unsigned)o[5] << 16);
        pk.w = (unsigned)o[6] | ((unsigned)o[7] << 16);
        *(uint4*)(h2 + (size_t)v * KP + fb) = pk;
    }
}

// ---------------- final: out = sigmoid(H @ H^T), 128x256 MFMA GEMM ----------------
// FINAL (revert to R10, session best 1093.8 us).  128x256 tile, 4 waves
// (1Mx4N), BK=32, 2 blocks/CU (write/compute overlap -- the R9 lever), depth-3
// A+B LDS ring with single barrier per K-step and counted vmcnt(6) (never
// drain-0 until the tail), setprio around MFMA, grouped-triangular decode
// (8 by-rows, bx-major: per-XCD working set < 4 MB L2 -- the R7 lever),
// XCD-bijective chunk swizzle.  Rect-tri coverage (bx >= by>>1), mirror
// stores write value-identical data on overlap.  K = 45*32 exactly, no tail.
// Verified plateau of the 9-variant family: ~310 us (~680 TF) with the
// 579-MB mandatory f32 output stream overlapped against compute.
__global__ __launch_bounds__(256, 2) void k_gemm_sig(const bf16_t* __restrict__ Hm,
                                                     float* __restrict__ out) {
    // XCD-bijective chunk swizzle (2256 = 8*282)
    int orig = blockIdx.x;
    int tt = (orig & 7) * (GRID_G / 8) + (orig >> 3);

    // grouped decode: groups of 8 by-rows (last 6), bx-major inside a group
    int u = tt, by0 = 88, R = 6;
#pragma unroll 1
    for (int g = 0; g < 12; ++g) {
        int Rg = (g == 11) ? 6 : 8;
        int sz = (g == 11) ? 12 : (364 - 32 * g);
        if (u < sz) { by0 = 8 * g; R = Rg; break; }
        u -= sz;
    }
    int d = 0;
#pragma unroll 1
    for (;;) {
        int s = 2 * d + 2; if (s > R) s = R;
        if (u < s) break;
        u -= s; ++d;
    }
    const int by = by0 + u;
    const int bx = (by0 >> 1) + d;

    __shared__ __align__(16) char lds[3 * 24576];   // ring: A 8KB + B 16KB per slot

    const int tid  = threadIdx.x;
    const int wave = tid >> 6, lane = tid & 63;
    const int rowA0 = by * 128;          // C rows
    const int colC0 = bx * 256;          // C cols = B rows
    const int r = lane & 15, q4 = lane >> 4;

    // staging source: thread covers 16 B at (row = c*64 + tid>>2, elem col = (tid&3)*8)
    const int srow = tid >> 2, scol = (tid & 3) * 8;
    const bf16_t* gA = Hm + (size_t)(rowA0 + srow) * KP + scol;
    const bf16_t* gB = Hm + (size_t)(colC0 + srow) * KP + scol;

    // fragment read offsets (row stride 64 B within a slot)
    const int aOff = r * 64 + q4 * 16;                       // + mi*1024
    const int bOff = 8192 + (wave * 64 + r) * 64 + q4 * 16;  // + ni*1024

    f32x4 acc[8][4] = {};

// stage K-step kt_ into ring slot sl_: 6 gload_lds per thread (2 A + 4 B)
#define STAGE(sl_, kt_) do {                                                      \
        const int k0_ = (kt_) * 32;                                               \
        char* base_ = lds + (sl_) * 24576;                                        \
        _Pragma("unroll")                                                         \
        for (int c_ = 0; c_ < 2; ++c_)                                            \
            __builtin_amdgcn_global_load_lds(                                     \
                (const __attribute__((address_space(1))) void*)(gA + (size_t)(c_ * 64) * KP + k0_), \
                (__attribute__((address_space(3))) void*)(base_ + c_ * 4096 + wave * 1024 + (lane & 63) * 16), \
                16, 0, 0);                                                        \
        _Pragma("unroll")                                                         \
        for (int c_ = 0; c_ < 4; ++c_)                                            \
            __builtin_amdgcn_global_load_lds(                                     \
                (const __attribute__((address_space(1))) void*)(gB + (size_t)(c_ * 64) * KP + k0_), \
                (__attribute__((address_space(3))) void*)(base_ + 8192 + c_ * 4096 + wave * 1024 + (lane & 63) * 16), \
                16, 0, 0);                                                        \
    } while (0)

    // prologue: stage tiles 0 and 1 (12 loads in flight)
    STAGE(0, 0); STAGE(1, 1);

    int slR = 0, slW = 2;   // read slot, write slot (= slR-1 mod 3)
#pragma unroll 1
    for (int kt = 0; kt < 45; ++kt) {
        // oldest 6 outstanding = tile kt's loads
        if (kt < 44) asm volatile("s_waitcnt vmcnt(6)" ::: "memory");
        else         asm volatile("s_waitcnt vmcnt(0)" ::: "memory");
        __builtin_amdgcn_s_barrier();          // tile kt in LDS; step kt-1 reads done
        __builtin_amdgcn_sched_barrier(0);
        if (kt + 2 < 45) STAGE(slW, kt + 2);   // re-stage the slot freed at kt-1

        const char* S = lds + slR * 24576;
        bf16x8 bfr[4], af[4];
#pragma unroll
        for (int ni = 0; ni < 4; ++ni)
            bfr[ni] = *(const bf16x8*)(S + bOff + ni * 1024);
#pragma unroll
        for (int mi = 0; mi < 4; ++mi)
            af[mi] = *(const bf16x8*)(S + aOff + mi * 1024);
        __builtin_amdgcn_s_setprio(1);
#pragma unroll
        for (int mi = 0; mi < 4; ++mi)
#pragma unroll
            for (int ni = 0; ni < 4; ++ni)
                acc[mi][ni] = __builtin_amdgcn_mfma_f32_16x16x32_bf16(af[mi], bfr[ni], acc[mi][ni], 0, 0, 0);
#pragma unroll
        for (int mi = 0; mi < 4; ++mi)
            af[mi] = *(const bf16x8*)(S + aOff + (mi + 4) * 1024);
#pragma unroll
        for (int mi = 0; mi < 4; ++mi)
#pragma unroll
            for (int ni = 0; ni < 4; ++ni)
                acc[mi + 4][ni] = __builtin_amdgcn_mfma_f32_16x16x32_bf16(af[mi], bfr[ni], acc[mi + 4][ni], 0, 0, 0);
        __builtin_amdgcn_s_setprio(0);
        __builtin_amdgcn_sched_barrier(0);

        slR = (slR == 2) ? 0 : slR + 1;
        slW = (slW == 2) ? 0 : slW + 1;
    }
#undef STAGE

    // epilogue. C/D layout: col=lane&15, row=(lane>>4)*4+reg. NNODES%4==0.
    // Direct store + unconditional mirror store (overlaps write equal values).
#pragma unroll
    for (int mi = 0; mi < 8; ++mi) {
        const int row0 = rowA0 + mi * 16 + q4 * 4;
#pragma unroll
        for (int ni = 0; ni < 4; ++ni) {
            const int col = colC0 + wave * 64 + ni * 16 + r;
            if (col < NNODES && row0 < NNODES) {
                f32x4 s;
#pragma unroll
                for (int r2 = 0; r2 < 4; ++r2)
                    s[r2] = 1.f / (1.f + __expf(-acc[mi][ni][r2]));
#pragma unroll
                for (int r2 = 0; r2 < 4; ++r2)
                    out[(size_t)(row0 + r2) * NNODES + col] = s[r2];
                *(f32x4*)(out + (size_t)col * NNODES + row0) = s;   // mirror
            }
        }
    }
}

extern "C" void kernel_launch(void* const* d_in, const int* in_sizes, int n_in,
                              void* d_out, int out_size, void* d_ws, size_t ws_size,
                              hipStream_t stream) {
    const bf16_t* x   = (const bf16_t*)d_in[0];
    const int*    ei  = (const int*)d_in[1];
    const bf16_t* W1  = (const bf16_t*)d_in[2];
    const bf16_t* as1 = (const bf16_t*)d_in[3];
    const bf16_t* ad1 = (const bf16_t*)d_in[4];
    const bf16_t* b1  = (const bf16_t*)d_in[5];
    const bf16_t* W2  = (const bf16_t*)d_in[6];
    const bf16_t* as2 = (const bf16_t*)d_in[7];
    const bf16_t* ad2 = (const bf16_t*)d_in[8];
    const bf16_t* b2  = (const bf16_t*)d_in[9];
    float* out = (float*)d_out;   // output 0 f32 [N][N], output 1 f32 [2][E]

    // Scratch lives inside d_out's adjacency region (576 MB f32), dead until
    // k_gemm_sig overwrites it. Only h2 (read during final GEMM) is in d_ws.
    char* obuf = (char*)d_out;
    size_t off = 0;
    auto carve = [&](size_t bytes) {
        char* p = obuf + off;
        off += (bytes + 255) & ~(size_t)255;
        return p;
    };
    float* h1pre  = (float*)carve((size_t)NNODES * FHID * 4);
    float* al1    = (float*)carve((size_t)NNODES * 4);
    float* ar1    = (float*)carve((size_t)NNODES * 4);
    float* h1     = (float*)carve((size_t)NNODES * FHID * 4);
    float* al2    = (float*)carve((size_t)NNODES * 4);
    float* ar2    = (float*)carve((size_t)NNODES * 4);
    int*   deg    = (int*)carve((size_t)NNODES * 4);
    int*   rowptr = (int*)carve((size_t)(NNODES + 1) * 4);
    int*   cursor = (int*)carve((size_t)NNODES * 4);
    int*   csrc   = (int*)carve((size_t)NETOT * 4);
    unsigned char* h2pre = (unsigned char*)carve((size_t)NNODES * KP);  // fp8
    bf16_t* h2 = (bf16_t*)d_ws;   // [MP][KP] bf16 = 34.65 MB
    (void)ws_size; (void)in_sizes; (void)n_in; (void)out_size;

    hipLaunchKernelGGL(k_init,    dim3(256), dim3(256), 0, stream, deg, h2);
    hipLaunchKernelGGL(k_count,   dim3((NEDGES + 255) / 256), dim3(256), 0, stream, ei, deg);
    hipLaunchKernelGGL(k_scan,    dim3(1), dim3(1024), 0, stream, deg, rowptr, cursor);
    hipLaunchKernelGGL(k_fill,    dim3((2 * NEDGES + 255) / 256), dim3(256), 0, stream,
                       ei, cursor, csrc, out);
    hipLaunchKernelGGL(k_linear1, dim3((NNODES + 255) / 256), dim3(256), 0, stream,
                       x, W1, as1, ad1, h1pre, al1, ar1);
    hipLaunchKernelGGL(k_agg1,    dim3(NNODES / 4), dim3(256), 0, stream,
                       h1pre, al1, ar1, rowptr, csrc, b1, h1);
    hipLaunchKernelGGL(k_linear2, dim3(NNODES / 4), dim3(256), 0, stream,
                       h1, W2, as2, ad2, h2pre, al2, ar2);
    hipLaunchKernelGGL(k_agg2,    dim3(NNODES), dim3(256), 0, stream,
                       h2pre, al2, ar2, rowptr, csrc, b2, h2);
    hipLaunchKernelGGL(k_gemm_sig, dim3(GRID_G), dim3(256), 0, stream, h2, out);
}